// Round 1
// baseline (6538.072 us; speedup 1.0000x reference)
//
#include <hip/hip_runtime.h>

#define B_    512
#define L_    16
#define IN_   128
#define H_    1024
#define T_    64
#define OUTROW 10240   /* (L_+T_)*IN_ */

typedef __attribute__((ext_vector_type(8))) short bf8;
typedef __attribute__((ext_vector_type(4))) float f4;
typedef unsigned short u16;
typedef unsigned int   u32;

__device__ __forceinline__ u16 f2bf(float f) {
    u32 u = __builtin_bit_cast(u32, f);
    u32 r = (u + 0x7fffu + ((u >> 16) & 1u)) >> 16;
    return (u16)r;
}
__device__ __forceinline__ float sigm(float x) { return 1.f / (1.f + __expf(-x)); }
__device__ __forceinline__ float tanh_f(float x) {
    float ax = fabsf(x);
    float e = __expf(-2.f * ax);
    float t = (1.f - e) / (1.f + e);
    return x < 0.f ? -t : t;
}

__device__ __forceinline__ void gl_lds16(const void* g, void* l) {
    __builtin_amdgcn_global_load_lds(
        (const __attribute__((address_space(1))) void*)g,
        (__attribute__((address_space(3))) void*)l, 16, 0, 0);
}

// ---- GEMM core: C[64 x 128] tile = A[64 x K] * B[128 x K]^T (both K-major bf16) ----
// Block = 512 threads (8 waves). Wave wv: rows (wv&3)*16, cols (wv>>2)*64 of the tile.
// A is split at K1: cols [0,K1) from pA0 (ld ldA0), cols [K1,K) from pA1 (ld ldA1).
__device__ __forceinline__ void gemm_core(
    const u16* pA0, int ldA0, int K1,
    const u16* pA1, int ldA1,
    const u16* pB, int ldB, int Ktot,
    int tm, int tn,
    u16* Alds, u16* Blds, f4 acc[4])
{
    const int tid  = threadIdx.x;
    const int lane = tid & 63;
    const int wv   = tid >> 6;       // 0..7
    const int wm   = wv & 3, wn = wv >> 2;
    const int l15  = lane & 15, qd = lane >> 4;
    const int lr   = lane >> 3;      // 0..7 : row within 8-row chunk
    const int lk   = (lane & 7) * 8; // k element offset (8 bf16 = 16B)

    const int arow  = tm * 64 + wv * 8 + lr;
    const int brow0 = tn * 128 + wv * 8 + lr;
    const int brow1 = tn * 128 + (wv + 8) * 8 + lr;

    u16* adst  = Alds + wv * 512;          // wv*1024 bytes
    u16* bdst0 = Blds + wv * 512;
    u16* bdst1 = Blds + (wv + 8) * 512;

    const u16* bsrc0 = pB + (size_t)brow0 * ldB + lk;
    const u16* bsrc1 = pB + (size_t)brow1 * ldB + lk;

    acc[0] = acc[1] = acc[2] = acc[3] = (f4)(0.f);

    for (int k0 = 0; k0 < Ktot; k0 += 64) {
        const u16* asrc;
        if (k0 < K1) asrc = pA0 + (size_t)arow * ldA0 + k0 + lk;
        else         asrc = pA1 + (size_t)arow * ldA1 + (k0 - K1) + lk;
        gl_lds16(asrc, adst);
        gl_lds16(bsrc0 + k0, bdst0);
        gl_lds16(bsrc1 + k0, bdst1);
        __syncthreads();   // drains vmcnt(0): LDS tile ready
#pragma unroll
        for (int s = 0; s < 2; ++s) {
            bf8 a = *(const bf8*)(Alds + (wm * 16 + l15) * 64 + s * 32 + qd * 8);
#pragma unroll
            for (int t = 0; t < 4; ++t) {
                bf8 b = *(const bf8*)(Blds + (wn * 64 + t * 16 + l15) * 64 + s * 32 + qd * 8);
                acc[t] = __builtin_amdgcn_mfma_f32_16x16x32_bf16(a, b, acc[t], 0, 0, 0);
            }
        }
        __syncthreads();   // before overwrite next iter
    }
}

// ---- LSTM layer: GEMM + fused cell epilogue ----
// Weight rows permuted: p = (u>>4)*64 + G*16 + (u&15), G in {i,f,g,o}. A wave's 4 acc
// tiles (col offsets 0,16,32,48 of its 64-col group) are gates i,f,g,o of unit
// u = tn*32 + wn*16 + (lane&15) -- all in-lane.
__global__ __launch_bounds__(512) void cell_gemm(
    const u16* pA0, int ldA0, int K1, const u16* pA1, int ldA1,
    const u16* pB, int Ktot,
    const float* __restrict__ bias, float* __restrict__ Cst, u16* __restrict__ Hdst)
{
    __shared__ __align__(16) u16 Alds[64 * 64];
    __shared__ __align__(16) u16 Blds[128 * 64];
    const int tn = blockIdx.x, tm = blockIdx.y;
    f4 acc[4];
    gemm_core(pA0, ldA0, K1, pA1, ldA1, pB, Ktot, Ktot, tm, tn, Alds, Blds, acc);

    const int tid = threadIdx.x, lane = tid & 63, wv = tid >> 6;
    const int wm = wv & 3, wn = wv >> 2, l15 = lane & 15, qd = lane >> 4;
    const int u  = tn * 32 + wn * 16 + l15;
    const int cb = tn * 128 + wn * 64 + l15;
    const float bi = bias[cb],      bf_ = bias[cb + 16];
    const float bg = bias[cb + 32], bo  = bias[cb + 48];
#pragma unroll
    for (int r = 0; r < 4; ++r) {
        const int row = tm * 64 + wm * 16 + qd * 4 + r;
        const float I  = sigm(acc[0][r] + bi);
        const float F  = sigm(acc[1][r] + bf_);
        const float Gg = tanh_f(acc[2][r] + bg);
        const float O  = sigm(acc[3][r] + bo);
        const size_t ix = (size_t)row * H_ + u;
        const float cn = F * Cst[ix] + I * Gg;
        Cst[ix] = cn;
        Hdst[ix] = f2bf(O * tanh_f(cn));
    }
}

// ---- Output projection: xl_new = xin + h1 @ Wout^T + b_out; writes XL (fp32),
// XLbf (bf16, feeds next L0) and the d_out time slot. Grid (1,8).
__global__ __launch_bounds__(512) void proj_gemm(
    const u16* pA, const u16* pB, const float* __restrict__ bout,
    const float* __restrict__ xin, int ldxin,
    float* __restrict__ XL, u16* __restrict__ XLbf,
    float* __restrict__ dout, int slot)
{
    __shared__ __align__(16) u16 Alds[64 * 64];
    __shared__ __align__(16) u16 Blds[128 * 64];
    const int tm = blockIdx.y;
    f4 acc[4];
    gemm_core(nullptr, 0, 0, pA, H_, pB, H_, H_, tm, 0, Alds, Blds, acc);

    const int tid = threadIdx.x, lane = tid & 63, wv = tid >> 6;
    const int wm = wv & 3, wn = wv >> 2, l15 = lane & 15, qd = lane >> 4;
#pragma unroll
    for (int t = 0; t < 4; ++t) {
        const int col = wn * 64 + t * 16 + l15;
        const float bo = bout[col];
#pragma unroll
        for (int r = 0; r < 4; ++r) {
            const int row = tm * 64 + wm * 16 + qd * 4 + r;
            const float v = xin[(size_t)row * ldxin + col] + acc[t][r] + bo;
            XL[row * IN_ + col] = v;
            XLbf[row * IN_ + col] = f2bf(v);
            dout[(size_t)row * OUTROW + slot * IN_ + col] = v;
        }
    }
}

// ---- Weight conversion: fp32 -> bf16, gate-permuted rows, fused biases ----
__global__ void conv_w(const float* Wih0, const float* Whh0, const float* bih0, const float* bhh0,
                       const float* Wih1, const float* Whh1, const float* bih1, const float* bhh1,
                       const float* Wout,
                       u16* W0c, float* b0p, u16* W1c, float* b1p, u16* Woutb)
{
    const int bid = blockIdx.x, tid = threadIdx.x;
    if (bid < 4096) {
        const int p = bid, rem = p & 63, G = rem >> 4, u = (p >> 6) * 16 + (rem & 15);
        const int src = G * H_ + u;
        for (int j = tid; j < IN_; j += 256)
            W0c[(size_t)p * 1152 + j] = f2bf(Wih0[(size_t)src * IN_ + j]);
        for (int j = tid; j < H_; j += 256)
            W0c[(size_t)p * 1152 + 128 + j] = f2bf(Whh0[(size_t)src * H_ + j]);
        if (tid == 0) b0p[p] = bih0[src] + bhh0[src];
    } else if (bid < 8192) {
        const int p = bid - 4096, rem = p & 63, G = rem >> 4, u = (p >> 6) * 16 + (rem & 15);
        const int src = G * H_ + u;
        for (int j = tid; j < H_; j += 256) {
            W1c[(size_t)p * 2048 + j]        = f2bf(Wih1[(size_t)src * H_ + j]);
            W1c[(size_t)p * 2048 + 1024 + j] = f2bf(Whh1[(size_t)src * H_ + j]);
        }
        if (tid == 0) b1p[p] = bih1[src] + bhh1[src];
    } else {
        const int r = bid - 8192; // 0..127
        for (int j = tid; j < H_; j += 256)
            Woutb[(size_t)r * H_ + j] = f2bf(Wout[(size_t)r * H_ + j]);
    }
}

// ---- Setup: zero states, x -> bf16 staging, x -> out[:, 0:16] copy ----
__global__ void setup_k(const float* __restrict__ x, u16* __restrict__ Xb,
                        u16* H0, u16* H1, float* c0, float* c1,
                        float* __restrict__ dout)
{
    const int i = blockIdx.x * 256 + threadIdx.x;  // < 512*16*128 = 1048576
    const float v = x[i];
    Xb[i] = f2bf(v);
    dout[(size_t)(i >> 11) * OUTROW + (i & 2047)] = v;
    if (i < B_ * H_) { H0[i] = 0; H1[i] = 0; c0[i] = 0.f; c1[i] = 0.f; }
}

extern "C" void kernel_launch(void* const* d_in, const int* in_sizes, int n_in,
                              void* d_out, int out_size, void* d_ws, size_t ws_size,
                              hipStream_t stream)
{
    const float* x    = (const float*)d_in[0];
    const float* Wih0 = (const float*)d_in[1];
    const float* Whh0 = (const float*)d_in[2];
    const float* bih0 = (const float*)d_in[3];
    const float* bhh0 = (const float*)d_in[4];
    const float* Wih1 = (const float*)d_in[5];
    const float* Whh1 = (const float*)d_in[6];
    const float* bih1 = (const float*)d_in[7];
    const float* bhh1 = (const float*)d_in[8];
    const float* Wout = (const float*)d_in[9];
    const float* bout = (const float*)d_in[10];
    float* dout = (float*)d_out;

    char* ws = (char*)d_ws;
    size_t off = 0;
    auto alloc = [&](size_t bytes) -> char* {
        char* p = ws + off; off += (bytes + 255) & ~(size_t)255; return p;
    };
    u16*  W0c   = (u16*)alloc(4096 * 1152 * 2);
    u16*  W1c   = (u16*)alloc(4096 * 2048 * 2);
    u16*  Woutb = (u16*)alloc(128 * 1024 * 2);
    float* b0p  = (float*)alloc(4096 * 4);
    float* b1p  = (float*)alloc(4096 * 4);
    u16*  Xb    = (u16*)alloc((size_t)B_ * L_ * IN_ * 2);
    u16*  H0b[2]; H0b[0] = (u16*)alloc((size_t)B_ * H_ * 2); H0b[1] = (u16*)alloc((size_t)B_ * H_ * 2);
    u16*  H1b[2]; H1b[0] = (u16*)alloc((size_t)B_ * H_ * 2); H1b[1] = (u16*)alloc((size_t)B_ * H_ * 2);
    float* c0   = (float*)alloc((size_t)B_ * H_ * 4);
    float* c1   = (float*)alloc((size_t)B_ * H_ * 4);
    float* XL   = (float*)alloc((size_t)B_ * IN_ * 4);
    u16*  XLbf  = (u16*)alloc((size_t)B_ * IN_ * 2);

    conv_w<<<8320, 256, 0, stream>>>(Wih0, Whh0, bih0, bhh0,
                                     Wih1, Whh1, bih1, bhh1, Wout,
                                     W0c, b0p, W1c, b1p, Woutb);
    setup_k<<<4096, 256, 0, stream>>>(x, Xb, H0b[0], H1b[0], c0, c1, dout);

    const dim3 cgrid(32, 8), pgrid(1, 8);
    int p = 0;
    for (int g = 0; g < 79; ++g) {   // 16 prompt + 63 rollout stack steps
        const u16* xpart; int ldx;
        if (g < 16) { xpart = Xb + g * IN_; ldx = L_ * IN_; }
        else        { xpart = XLbf;         ldx = IN_; }
        cell_gemm<<<cgrid, 512, 0, stream>>>(xpart, ldx, IN_, H0b[p], H_,
                                             W0c, IN_ + H_, b0p, c0, H0b[1 - p]);
        cell_gemm<<<cgrid, 512, 0, stream>>>(H0b[1 - p], H_, H_, H1b[p], H_,
                                             W1c, 2 * H_, b1p, c1, H1b[1 - p]);
        if (g >= 15) {
            const int s = g - 15;            // 0..63 -> out slot 16+s
            const float* xin; int ldxin;
            if (s == 0) { xin = x + 15 * IN_; ldxin = L_ * IN_; }
            else        { xin = XL;           ldxin = IN_; }
            proj_gemm<<<pgrid, 512, 0, stream>>>(H1b[1 - p], Woutb, bout,
                                                 xin, ldxin, XL, XLbf, dout, 16 + s);
        }
        p ^= 1;
    }
}

// Round 3
// 4944.947 us; speedup vs baseline: 1.3222x; 1.3222x over previous
//
#include <hip/hip_runtime.h>

#define B_    512
#define L_    16
#define IN_   128
#define H_    1024
#define T_    64
#define OUTROW 10240   /* (L_+T_)*IN_ */

typedef __attribute__((ext_vector_type(8))) short bf8;
typedef __attribute__((ext_vector_type(4))) float f4;
typedef unsigned short u16;
typedef unsigned int   u32;

__device__ __forceinline__ u16 f2bf(float f) {
    u32 u = __builtin_bit_cast(u32, f);
    u32 r = (u + 0x7fffu + ((u >> 16) & 1u)) >> 16;
    return (u16)r;
}
__device__ __forceinline__ float sigm(float x) { return 1.f / (1.f + __expf(-x)); }
__device__ __forceinline__ float tanh_f(float x) {
    float ax = fabsf(x);
    float e = __expf(-2.f * ax);
    float t = (1.f - e) / (1.f + e);
    return x < 0.f ? -t : t;
}

__device__ __forceinline__ void gl_lds16(const u16* g, u16* l) {
    __builtin_amdgcn_global_load_lds(
        (const __attribute__((address_space(1))) void*)g,
        (__attribute__((address_space(3))) void*)l, 16, 0, 0);
}

// ---- K-loop macro: accumulates C[64x64] += A_seg[64 x NK*64] * B_seg[64 x NK*64]^T.
// Single wave (64 threads). Requires in scope: lane-derived lr, lc, l15, qd, sw,
// LDS buffers Alds/Blds (64x64 u16 each), and f4 acc[4][4].
// PA/PB point at (row 0, k 0) of this segment; LDA/LDB are row strides (elements).
// XOR swizzle: logical 16B chunk c of row r is stored at physical chunk c^(r&7);
// staging permutes the global source chunk per lane (LDS dst is HW-fixed at
// base+lane*16); reads XOR the same mask -> conflict-free ds_read_b128.
#define GEMM_TILES(PA, LDA, PB, LDB, NK)                                          \
  do {                                                                            \
    const u16* aP_ = (PA) + (size_t)lr * (LDA) + lc;                              \
    const u16* bP_ = (PB) + (size_t)lr * (LDB) + lc;                              \
    for (int kt_ = 0; kt_ < (NK); ++kt_) {                                        \
      _Pragma("unroll")                                                           \
      for (int i_ = 0; i_ < 8; ++i_) {                                            \
        gl_lds16(aP_ + (size_t)(i_ * 8) * (LDA) + kt_ * 64, Alds + i_ * 512);     \
        gl_lds16(bP_ + (size_t)(i_ * 8) * (LDB) + kt_ * 64, Blds + i_ * 512);     \
      }                                                                           \
      __syncthreads();                                                            \
      _Pragma("unroll")                                                           \
      for (int s_ = 0; s_ < 2; ++s_) {                                            \
        const int ch_ = (s_ * 4 + qd) ^ sw;                                       \
        bf8 aa_[4], bb_[4];                                                       \
        _Pragma("unroll")                                                         \
        for (int g_ = 0; g_ < 4; ++g_)                                            \
          aa_[g_] = *(const bf8*)(Alds + (g_ * 16 + l15) * 64 + ch_ * 8);         \
        _Pragma("unroll")                                                         \
        for (int g_ = 0; g_ < 4; ++g_)                                            \
          bb_[g_] = *(const bf8*)(Blds + (g_ * 16 + l15) * 64 + ch_ * 8);         \
        _Pragma("unroll")                                                         \
        for (int g_ = 0; g_ < 4; ++g_) {                                          \
          _Pragma("unroll")                                                       \
          for (int t_ = 0; t_ < 4; ++t_)                                          \
            acc[g_][t_] = __builtin_amdgcn_mfma_f32_16x16x32_bf16(                \
                aa_[g_], bb_[t_], acc[g_][t_], 0, 0, 0);                          \
        }                                                                         \
      }                                                                           \
      __syncthreads();                                                            \
    }                                                                             \
  } while (0)

#define LANE_SETUP                                                                \
    const int lane = threadIdx.x & 63;                                            \
    const int l15 = lane & 15, qd = lane >> 4;                                    \
    const int lr  = lane >> 3;                                                    \
    const int lc  = ((lane & 7) ^ lr) * 8;                                        \
    const int sw  = l15 & 7;                                                      \
    f4 acc[4][4];                                                                 \
    _Pragma("unroll")                                                             \
    for (int g_ = 0; g_ < 4; ++g_) {                                              \
      _Pragma("unroll")                                                           \
      for (int t_ = 0; t_ < 4; ++t_) acc[g_][t_] = (f4)(0.f);                     \
    }

// ---- LSTM layer: GEMM over concat(A0[K1], A1[Ktot-K1]) + fused cell epilogue.
// Weight rows permuted p = (u>>4)*64 + G*16 + (u&15); a block's 64-col group =
// gates i,f,g,o (acc col-tiles 0..3) of units u = tn*16 + l15 -- all in-lane.
__global__ __launch_bounds__(64) void cell_gemm(
    const u16* __restrict__ pA0, int ldA0, int K1,
    const u16* __restrict__ pA1, int ldA1,
    const u16* __restrict__ pB, int Ktot,
    const float* __restrict__ bias, float* __restrict__ Cst, u16* __restrict__ Hdst)
{
    __shared__ __align__(16) u16 Alds[64 * 64];
    __shared__ __align__(16) u16 Blds[64 * 64];
    const int tn = blockIdx.x, tm = blockIdx.y;
    LANE_SETUP
    const u16* b0 = pB + (size_t)(tn * 64) * Ktot;
    GEMM_TILES(pA0 + (size_t)(tm * 64) * ldA0, ldA0, b0, Ktot, K1 >> 6);
    GEMM_TILES(pA1 + (size_t)(tm * 64) * ldA1, ldA1, b0 + K1, Ktot, (Ktot - K1) >> 6);

    const int u  = tn * 16 + l15;
    const int cb = tn * 64 + l15;
    const float bi = bias[cb],      bf_ = bias[cb + 16];
    const float bg = bias[cb + 32], bo  = bias[cb + 48];
#pragma unroll
    for (int rg = 0; rg < 4; ++rg) {
#pragma unroll
        for (int r = 0; r < 4; ++r) {
            const int row = tm * 64 + rg * 16 + qd * 4 + r;
            const float I  = sigm(acc[rg][0][r] + bi);
            const float F  = sigm(acc[rg][1][r] + bf_);
            const float Gg = tanh_f(acc[rg][2][r] + bg);
            const float O  = sigm(acc[rg][3][r] + bo);
            const size_t ix = (size_t)row * H_ + u;
            const float cn = F * Cst[ix] + I * Gg;
            Cst[ix] = cn;
            Hdst[ix] = f2bf(O * tanh_f(cn));
        }
    }
}

// ---- Output projection, split-K=4 partials: PP[ks][512][128] ----
__global__ __launch_bounds__(64) void proj_part(
    const u16* __restrict__ pA, const u16* __restrict__ pB,
    float* __restrict__ PP)
{
    __shared__ __align__(16) u16 Alds[64 * 64];
    __shared__ __align__(16) u16 Blds[64 * 64];
    const int tn = blockIdx.x, tm = blockIdx.y, ks = blockIdx.z;
    LANE_SETUP
    GEMM_TILES(pA + (size_t)(tm * 64) * H_ + ks * 256, H_,
               pB + (size_t)(tn * 64) * H_ + ks * 256, H_, 4);

    float* dst = PP + (size_t)ks * (B_ * IN_);
#pragma unroll
    for (int rg = 0; rg < 4; ++rg)
#pragma unroll
        for (int t = 0; t < 4; ++t)
#pragma unroll
            for (int r = 0; r < 4; ++r) {
                const int row = tm * 64 + rg * 16 + qd * 4 + r;
                const int col = tn * 64 + t * 16 + l15;
                dst[(size_t)row * IN_ + col] = acc[rg][t][r];
            }
}

// ---- Finalize: xl = xin + sum(PP) + b_out; write XL (fp32), XLbf, dout slot ----
__global__ void proj_fin(const float* __restrict__ PP,
                         const float* __restrict__ xin, int ldxin,
                         const float* __restrict__ bout,
                         float* __restrict__ XL, u16* __restrict__ XLbf,
                         float* __restrict__ dout, int slot)
{
    const int i = blockIdx.x * 256 + threadIdx.x;   // < 65536
    const int row = i >> 7, col = i & 127;
    const float v = xin[(size_t)row * ldxin + col] + bout[col]
                  + PP[i] + PP[B_ * IN_ + i] + PP[2 * B_ * IN_ + i] + PP[3 * B_ * IN_ + i];
    XL[i] = v;
    XLbf[i] = f2bf(v);
    dout[(size_t)row * OUTROW + slot * IN_ + col] = v;
}

// ---- Weight conversion: fp32 -> bf16, gate-permuted rows, fused biases ----
__global__ void conv_w(const float* Wih0, const float* Whh0, const float* bih0, const float* bhh0,
                       const float* Wih1, const float* Whh1, const float* bih1, const float* bhh1,
                       const float* Wout,
                       u16* W0c, float* b0p, u16* W1c, float* b1p, u16* Woutb)
{
    const int bid = blockIdx.x, tid = threadIdx.x;
    if (bid < 4096) {
        const int p = bid, rem = p & 63, G = rem >> 4, u = (p >> 6) * 16 + (rem & 15);
        const int src = G * H_ + u;
        for (int j = tid; j < IN_; j += 256)
            W0c[(size_t)p * 1152 + j] = f2bf(Wih0[(size_t)src * IN_ + j]);
        for (int j = tid; j < H_; j += 256)
            W0c[(size_t)p * 1152 + 128 + j] = f2bf(Whh0[(size_t)src * H_ + j]);
        if (tid == 0) b0p[p] = bih0[src] + bhh0[src];
    } else if (bid < 8192) {
        const int p = bid - 4096, rem = p & 63, G = rem >> 4, u = (p >> 6) * 16 + (rem & 15);
        const int src = G * H_ + u;
        for (int j = tid; j < H_; j += 256) {
            W1c[(size_t)p * 2048 + j]        = f2bf(Wih1[(size_t)src * H_ + j]);
            W1c[(size_t)p * 2048 + 1024 + j] = f2bf(Whh1[(size_t)src * H_ + j]);
        }
        if (tid == 0) b1p[p] = bih1[src] + bhh1[src];
    } else {
        const int r = bid - 8192; // 0..127
        for (int j = tid; j < H_; j += 256)
            Woutb[(size_t)r * H_ + j] = f2bf(Wout[(size_t)r * H_ + j]);
    }
}

// ---- Setup: zero states, x -> bf16 staging, x -> out[:, 0:16] copy ----
__global__ void setup_k(const float* __restrict__ x, u16* __restrict__ Xb,
                        u16* H0, u16* H1, float* c0, float* c1,
                        float* __restrict__ dout)
{
    const int i = blockIdx.x * 256 + threadIdx.x;  // < 512*16*128 = 1048576
    const float v = x[i];
    Xb[i] = f2bf(v);
    dout[(size_t)(i >> 11) * OUTROW + (i & 2047)] = v;
    if (i < B_ * H_) { H0[i] = 0; H1[i] = 0; c0[i] = 0.f; c1[i] = 0.f; }
}

extern "C" void kernel_launch(void* const* d_in, const int* in_sizes, int n_in,
                              void* d_out, int out_size, void* d_ws, size_t ws_size,
                              hipStream_t stream)
{
    const float* x    = (const float*)d_in[0];
    const float* Wih0 = (const float*)d_in[1];
    const float* Whh0 = (const float*)d_in[2];
    const float* bih0 = (const float*)d_in[3];
    const float* bhh0 = (const float*)d_in[4];
    const float* Wih1 = (const float*)d_in[5];
    const float* Whh1 = (const float*)d_in[6];
    const float* bih1 = (const float*)d_in[7];
    const float* bhh1 = (const float*)d_in[8];
    const float* Wout = (const float*)d_in[9];
    const float* bout = (const float*)d_in[10];
    float* dout = (float*)d_out;

    char* ws = (char*)d_ws;
    size_t off = 0;
    auto alloc = [&](size_t bytes) -> char* {
        char* p = ws + off; off += (bytes + 255) & ~(size_t)255; return p;
    };
    u16*  W0c   = (u16*)alloc(4096 * 1152 * 2);
    u16*  W1c   = (u16*)alloc(4096 * 2048 * 2);
    u16*  Woutb = (u16*)alloc(128 * 1024 * 2);
    float* b0p  = (float*)alloc(4096 * 4);
    float* b1p  = (float*)alloc(4096 * 4);
    u16*  Xb    = (u16*)alloc((size_t)B_ * L_ * IN_ * 2);
    u16*  H0b[2]; H0b[0] = (u16*)alloc((size_t)B_ * H_ * 2); H0b[1] = (u16*)alloc((size_t)B_ * H_ * 2);
    u16*  H1b[2]; H1b[0] = (u16*)alloc((size_t)B_ * H_ * 2); H1b[1] = (u16*)alloc((size_t)B_ * H_ * 2);
    float* c0   = (float*)alloc((size_t)B_ * H_ * 4);
    float* c1   = (float*)alloc((size_t)B_ * H_ * 4);
    float* XL   = (float*)alloc((size_t)B_ * IN_ * 4);
    u16*  XLbf  = (u16*)alloc((size_t)B_ * IN_ * 2);
    float* PP   = (float*)alloc((size_t)4 * B_ * IN_ * 4);

    conv_w<<<8320, 256, 0, stream>>>(Wih0, Whh0, bih0, bhh0,
                                     Wih1, Whh1, bih1, bhh1, Wout,
                                     W0c, b0p, W1c, b1p, Woutb);
    setup_k<<<4096, 256, 0, stream>>>(x, Xb, H0b[0], H1b[0], c0, c1, dout);

    const dim3 cgrid(64, 8), pgrid(2, 8, 4);
    int p = 0;
    for (int g = 0; g < 79; ++g) {   // 16 prompt + 63 rollout stack steps
        const u16* xpart; int ldx;
        if (g < 16) { xpart = Xb + g * IN_; ldx = L_ * IN_; }
        else        { xpart = XLbf;         ldx = IN_; }
        cell_gemm<<<cgrid, 64, 0, stream>>>(xpart, ldx, IN_, H0b[p], H_,
                                            W0c, IN_ + H_, b0p, c0, H0b[1 - p]);
        cell_gemm<<<cgrid, 64, 0, stream>>>(H0b[1 - p], H_, H_, H1b[p], H_,
                                            W1c, 2 * H_, b1p, c1, H1b[1 - p]);
        if (g >= 15) {
            const int s = g - 15;            // 0..63 -> out slot 16+s
            proj_part<<<pgrid, 64, 0, stream>>>(H1b[1 - p], Woutb, PP);
            const float* xin; int ldxin;
            if (s == 0) { xin = x + 15 * IN_; ldxin = L_ * IN_; }
            else        { xin = XL;           ldxin = IN_; }
            proj_fin<<<256, 256, 0, stream>>>(PP, xin, ldxin, bout,
                                              XL, XLbf, dout, 16 + s);
        }
        p ^= 1;
    }
}